// Round 7
// baseline (472.089 us; speedup 1.0000x reference)
//
#include <hip/hip_runtime.h>

#define B_ 8
#define C_ 3
#define H_ 256
#define W_ 256
#define HID_ 32
#define HW_ (H_*W_)            // 65536
#define N_ (B_*H_*W_)          // 524288
#define K01_ 0xBDCCCCCDu       // fkey(0.1f)
#define TILE_ 16
#define NB4_ (N_/4)            // 131072

__device__ __forceinline__ unsigned fkey(float f){
  unsigned u = __float_as_uint(f);
  return (u & 0x80000000u) ? ~u : (u | 0x80000000u);
}

// mk entry: [63:56]=tag(it+1) | [55:24]=fkey(sim) | [23:0]=neighbor id (N<2^24).
// atomicMax: newer tag always wins; same tag -> (key,id) lexicographic max,
// which is exactly the reference's "max rb among sim==maxsim" tie-break.
__device__ __forceinline__ unsigned long long pack_mk(unsigned tag, unsigned key, int id){
  return ((unsigned long long)tag << 56) | ((unsigned long long)key << 24) | (unsigned)id;
}

__device__ __forceinline__ int parent_dec(unsigned long long m, unsigned tag, int x){
  if ((unsigned)(m >> 56) != tag) return x;
  return ((unsigned)(m >> 24) > K01_) ? (int)(m & 0xFFFFFFu) : x;
}

// 16x16-tile conv + init + it0 in-tile sims.
// img tile staged in LDS (few coalesced loads, bounds checks at stage time);
// acc stays in registers; right/down sims via wave shuffles (lane layout:
// r = wv*4 + (lane>>4), c = lane&15) + small LDS buffer for cross-wave rows.
// Cross-tile edges are handled by k_bedge.
__global__ __launch_bounds__(256) void k_conv_init(const float* __restrict__ img,
    const float* __restrict__ cw, const float* __restrict__ cb,
    float* __restrict__ fsum, int* __restrict__ labels,
    float* __restrict__ cnt, float* __restrict__ psum,
    unsigned long long* __restrict__ mk){
  __shared__ float w_s[HID_*C_*9];
  __shared__ float b_s[HID_];
  __shared__ float img_s[C_][TILE_+2][TILE_+3];   // 3 x 18 x 19
  __shared__ float rowbuf[3*TILE_][33];           // rows 4,8,12 for cross-wave down
  for (int t = threadIdx.x; t < HID_*C_*9; t += blockDim.x) w_s[t] = cw[t];
  if (threadIdx.x < HID_) b_s[threadIdx.x] = cb[threadIdx.x];

  int b  = blockIdx.x >> 8;
  int ti = blockIdx.x & 255;
  int h0 = (ti >> 4) * TILE_;
  int w0 = (ti & 15) * TILE_;

  // stage img tile (18x18x3) with zero padding
  for (int t = threadIdx.x; t < C_*18*18; t += blockDim.x){
    int ci = t / 324; int rm = t - ci*324; int rr = rm / 18; int cc = rm - rr*18;
    int hh = h0 - 1 + rr, ww = w0 - 1 + cc;
    float v = 0.f;
    if (hh >= 0 && hh < H_ && ww >= 0 && ww < W_)
      v = img[(size_t)(b*C_+ci)*HW_ + hh*W_ + ww];
    img_s[ci][rr][cc] = v;
  }
  __syncthreads();

  int lane = threadIdx.x & 63, wv = threadIdx.x >> 6;
  int r = wv*4 + (lane >> 4);
  int c = lane & 15;
  int h = h0 + r, w = w0 + c;
  int i = (b << 16) | (h << 8) | w;

  float patch[C_*9];
  #pragma unroll
  for (int ci=0; ci<C_; ++ci)
    #pragma unroll
    for (int kh=0; kh<3; ++kh)
      #pragma unroll
      for (int kw=0; kw<3; ++kw)
        patch[ci*9+kh*3+kw] = img_s[ci][r+kh][c+kw];

  float acc[HID_];
  #pragma unroll 4
  for (int oc=0; oc<HID_; ++oc){
    float a = b_s[oc];
    const float* ws = w_s + oc*C_*9;
    #pragma unroll
    for (int t=0; t<C_*9; ++t) a += patch[t]*ws[t];
    acc[oc] = a;
  }

  // fsum store (direct; conv is latency-bound, not store-bound)
  {
    float4* o4 = (float4*)(fsum + (size_t)i*HID_);
    #pragma unroll
    for (int k=0; k<HID_/4; ++k)
      o4[k] = make_float4(acc[4*k], acc[4*k+1], acc[4*k+2], acc[4*k+3]);
  }
  labels[i] = i;
  cnt[i] = 1.0f;
  #pragma unroll
  for (int cc=0; cc<C_; ++cc) psum[(size_t)i*C_+cc] = img_s[cc][r+1][c+1];

  // stage rows 4,8,12 (each wave's lanes 0..15) for cross-wave down edges
  if (wv >= 1 && lane < 16){
    float* dst = rowbuf[(wv-1)*TILE_ + c];
    #pragma unroll
    for (int d=0; d<HID_; ++d) dst[d] = acc[d];
  }

  // right edge via shfl_down(1); valid for c<15
  float d2R = 0.f;
  #pragma unroll
  for (int k=0; k<HID_/4; ++k){
    float t0 = acc[4*k]   - __shfl_down(acc[4*k],  1);
    float t1 = acc[4*k+1] - __shfl_down(acc[4*k+1],1);
    float t2 = acc[4*k+2] - __shfl_down(acc[4*k+2],1);
    float t3 = acc[4*k+3] - __shfl_down(acc[4*k+3],1);
    d2R += t0*t0 + t1*t1 + t2*t2 + t3*t3;
  }
  // down edge via shfl_down(16) for lanes<48
  float d2D = 0.f;
  #pragma unroll
  for (int k=0; k<HID_/4; ++k){
    float t0 = acc[4*k]   - __shfl_down(acc[4*k],  16);
    float t1 = acc[4*k+1] - __shfl_down(acc[4*k+1],16);
    float t2 = acc[4*k+2] - __shfl_down(acc[4*k+2],16);
    float t3 = acc[4*k+3] - __shfl_down(acc[4*k+3],16);
    d2D += t0*t0 + t1*t1 + t2*t2 + t3*t3;
  }
  __syncthreads();
  if (lane >= 48 && wv < 3){          // row 4wv+3: neighbor row held by wave wv+1
    const float* nb = rowbuf[wv*TILE_ + c];
    d2D = 0.f;
    #pragma unroll
    for (int k=0; k<HID_/4; ++k){
      float t0 = acc[4*k]   - nb[4*k];
      float t1 = acc[4*k+1] - nb[4*k+1];
      float t2 = acc[4*k+2] - nb[4*k+2];
      float t3 = acc[4*k+3] - nb[4*k+3];
      d2D += t0*t0 + t1*t1 + t2*t2 + t3*t3;
    }
  }

  if (c < TILE_-1){
    unsigned key = fkey(expf(-d2R));
    atomicMax(mk+i,   pack_mk(1u, key, i+1));
    atomicMax(mk+i+1, pack_mk(1u, key, i));
  }
  if (r < TILE_-1){
    unsigned key = fkey(expf(-d2D));
    atomicMax(mk+i,     pack_mk(1u, key, i+W_));
    atomicMax(mk+i+W_,  pack_mk(1u, key, i));
  }
}

// cross-tile it0 edges: 8 images x {15 boundary cols x 256, 15 boundary rows x 256}
__global__ void k_bedge(const float* __restrict__ fsum,
                        unsigned long long* __restrict__ mk){
  int t = blockIdx.x*blockDim.x + threadIdx.x;
  if (t >= B_*2*15*256) return;
  int y  = t & 255;
  int k  = (t >> 8) % 15;
  int ty = (t >> 8) / 15;
  int b  = ty >> 1, tp = ty & 1;
  int i, j;
  if (tp == 0){ i = (b<<16) | (y<<8) | (16*k+15); j = i+1;  }
  else        { i = (b<<16) | ((16*k+15)<<8) | y; j = i+W_; }
  const float4* fa = (const float4*)(fsum + (size_t)i*HID_);
  const float4* fb = (const float4*)(fsum + (size_t)j*HID_);
  float d2 = 0.f;
  #pragma unroll
  for (int q=0; q<HID_/4; ++q){
    float4 va = fa[q], vb = fb[q];
    float t0 = va.x-vb.x, t1 = va.y-vb.y, t2 = va.z-vb.z, t3 = va.w-vb.w;
    d2 += t0*t0 + t1*t1 + t2*t2 + t3*t3;
  }
  unsigned key = fkey(expf(-d2));
  atomicMax(mk+i, pack_mk(1u, key, j));
  atomicMax(mk+j, pack_mk(1u, key, i));
}

// mid-iteration fused sim+best, 4 px/thread, uniform-region early exit.
__global__ void k_simbest(const int* __restrict__ labels,
                          const float* __restrict__ fsum, const float* __restrict__ cnt,
                          unsigned long long* __restrict__ mk, unsigned tag){
  int q = blockIdx.x*blockDim.x + threadIdx.x;
  if (q >= NB4_) return;
  int i0 = q*4;
  int rem = i0 & (HW_-1); int h = rem >> 8; int w = rem & (W_-1);
  int4 L = *(const int4*)(labels+i0);
  bool hasD = (h < H_-1);
  int4 LD = hasD ? *(const int4*)(labels+i0+W_) : L;
  int L4 = (w+4 < W_) ? labels[i0+4] : L.w;
  if (L.x==L.y && L.y==L.z && L.z==L.w && L.w==L4 &&
      L.x==LD.x && LD.x==LD.y && LD.y==LD.z && LD.z==LD.w) return;
  int Ls[5]  = {L.x, L.y, L.z, L.w, L4};
  int LDs[4] = {LD.x, LD.y, LD.z, LD.w};
  int curRi = -1;
  float4 mi[HID_/4];
  for (int j=0; j<4; ++j){
    int ri = Ls[j];
    int rR = (w+j < W_-1) ? Ls[j+1] : ri;
    int rD = hasD ? LDs[j] : ri;
    bool eR = (rR != ri), eD = (rD != ri);
    if (!eR && !eD) continue;
    if (ri != curRi){
      float rci = 1.0f / cnt[ri];
      const float4* fi = (const float4*)(fsum + (size_t)ri*HID_);
      #pragma unroll
      for (int k=0; k<HID_/4; ++k){
        float4 v = fi[k];
        mi[k] = make_float4(v.x*rci, v.y*rci, v.z*rci, v.w*rci);
      }
      curRi = ri;
    }
    int i = i0 + j;
    if (eR){
      float rcj = 1.0f / cnt[rR];
      const float4* fj = (const float4*)(fsum + (size_t)rR*HID_);
      float d2 = 0.f;
      #pragma unroll
      for (int k=0; k<HID_/4; ++k){
        float4 v = fj[k];
        float tx = mi[k].x - v.x*rcj; float ty = mi[k].y - v.y*rcj;
        float tz = mi[k].z - v.z*rcj; float tw = mi[k].w - v.w*rcj;
        d2 += tx*tx + ty*ty + tz*tz + tw*tw;
      }
      unsigned key = fkey(expf(-d2));
      atomicMax(mk+ri, pack_mk(tag, key, rR));
      atomicMax(mk+rR, pack_mk(tag, key, ri));
    }
    if (eD){
      float rcj = 1.0f / cnt[rD];
      const float4* fj = (const float4*)(fsum + (size_t)rD*HID_);
      float d2 = 0.f;
      #pragma unroll
      for (int k=0; k<HID_/4; ++k){
        float4 v = fj[k];
        float tx = mi[k].x - v.x*rcj; float ty = mi[k].y - v.y*rcj;
        float tz = mi[k].z - v.z*rcj; float tw = mi[k].w - v.w*rcj;
        d2 += tx*tx + ty*ty + tz*tz + tw*tw;
      }
      unsigned key = fkey(expf(-d2));
      atomicMax(mk+ri, pack_mk(tag, key, rD));
      atomicMax(mk+rD, pack_mk(tag, key, ri));
    }
  }
}

// chase + fold + relabel, 4 px/thread with per-thread root cache.
__global__ void k_update(const unsigned long long* __restrict__ mk, unsigned tag,
                         int* __restrict__ labels,
                         float* __restrict__ fsum, float* __restrict__ psum,
                         float* __restrict__ cnt){
  int q = blockIdx.x*blockDim.x + threadIdx.x;
  if (q >= NB4_) return;
  int i0 = q*4;
  int4 L = *(const int4*)(labels+i0);
  int ls[4] = {L.x, L.y, L.z, L.w};
  int xs[4];
  int prevL = -1, prevX = -1;
  for (int j=0; j<4; ++j){
    int l = ls[j];
    int x;
    if (l == prevL) x = prevX;
    else {
      x = l;
      for (int it = 0; it < (1<<20); ++it){
        int p = parent_dec(mk[x], tag, x);
        if (p == x) break;
        int pp = parent_dec(mk[p], tag, p);
        if (pp == x && x < p) break;   // broken 2-cycle: x is the root
        x = p;
      }
      prevL = l; prevX = x;
    }
    xs[j] = x;
    int i = i0 + j;
    if (l == i && x != i){             // dying root: fold into surviving root
      atomicAdd(cnt+x, cnt[i]);
      const float* s = fsum + (size_t)i*HID_;
      float* ds = fsum + (size_t)x*HID_;
      #pragma unroll
      for (int d=0; d<HID_; ++d) atomicAdd(ds+d, s[d]);
      const float* ps = psum + (size_t)i*C_;
      float* dp = psum + (size_t)x*C_;
      #pragma unroll
      for (int cc=0; cc<C_; ++cc) atomicAdd(dp+cc, ps[cc]);
    }
  }
  *(int4*)(labels+i0) = make_int4(xs[0], xs[1], xs[2], xs[3]);
}

// finalize, 4 px/thread: region feature recomputed at root (cached across the
// 4 px), mean injection, labels as float.
__global__ __launch_bounds__(256) void k_out(const int* __restrict__ labels,
      const float* __restrict__ img, const float* __restrict__ cnt,
      const float* __restrict__ fsum, const float* __restrict__ psum,
      const float* __restrict__ lw, const float* __restrict__ lb,
      float* __restrict__ out, float* __restrict__ outlab){
  __shared__ float lw_s[C_*HID_];
  __shared__ float lb_s[C_];
  for (int t = threadIdx.x; t < C_*HID_; t += blockDim.x) lw_s[t] = lw[t];
  if (threadIdx.x < C_) lb_s[threadIdx.x] = lb[threadIdx.x];
  __syncthreads();
  int q = blockIdx.x*blockDim.x + threadIdx.x;
  if (q >= NB4_) return;
  int i0 = q*4;
  int b = i0 >> 16; int rem = i0 & (HW_-1);
  int4 L = *(const int4*)(labels+i0);
  int ls[4] = {L.x, L.y, L.z, L.w};
  float4 iv[C_];
  #pragma unroll
  for (int cc=0; cc<C_; ++cc)
    iv[cc] = *(const float4*)(img + (size_t)(b*C_+cc)*HW_ + rem);
  float vals[12];
  float rf[C_];
  int prevL = -1;
  for (int j=0; j<4; ++j){
    int l = ls[j];
    if (l != prevL){
      float rc = 1.0f / cnt[l];
      const float* s = fsum + (size_t)l*HID_;
      #pragma unroll
      for (int cc=0; cc<C_; ++cc){
        float a = 0.f;
        const float* wv = lw_s + cc*HID_;
        #pragma unroll
        for (int d=0; d<HID_; ++d) a += (s[d]*rc)*wv[d];
        rf[cc] = (a + lb_s[cc]) - psum[(size_t)l*C_+cc]*rc;
      }
      prevL = l;
    }
    vals[j*3+0] = rf[0]; vals[j*3+1] = rf[1]; vals[j*3+2] = rf[2];
  }
  vals[0]  += iv[0].x; vals[1]  += iv[1].x; vals[2]  += iv[2].x;
  vals[3]  += iv[0].y; vals[4]  += iv[1].y; vals[5]  += iv[2].y;
  vals[6]  += iv[0].z; vals[7]  += iv[1].z; vals[8]  += iv[2].z;
  vals[9]  += iv[0].w; vals[10] += iv[1].w; vals[11] += iv[2].w;
  float4* o4 = (float4*)(out + (size_t)i0*C_);
  o4[0] = make_float4(vals[0], vals[1], vals[2],  vals[3]);
  o4[1] = make_float4(vals[4], vals[5], vals[6],  vals[7]);
  o4[2] = make_float4(vals[8], vals[9], vals[10], vals[11]);
  *(float4*)(outlab + i0) =
      make_float4((float)ls[0], (float)ls[1], (float)ls[2], (float)ls[3]);
}

extern "C" void kernel_launch(void* const* d_in, const int* in_sizes, int n_in,
                              void* d_out, int out_size, void* d_ws, size_t ws_size,
                              hipStream_t stream) {
  const float* img = (const float*)d_in[0];
  const float* cw  = (const float*)d_in[1];
  const float* cb  = (const float*)d_in[2];
  const float* lw  = (const float*)d_in[3];
  const float* lb  = (const float*)d_in[4];

  char* ws = (char*)d_ws;
  size_t off = 0;
  auto alloc = [&](size_t bytes) -> void* {
    void* p = ws + off; off += (bytes + 255) & ~(size_t)255; return p;
  };
  float*              fsum   = (float*)              alloc((size_t)N_*HID_*4);
  float*              psum   = (float*)              alloc((size_t)N_*C_*4);
  float*              cnt    = (float*)              alloc((size_t)N_*4);
  unsigned long long* mk     = (unsigned long long*) alloc((size_t)N_*8);
  int*                labels = (int*)                alloc((size_t)N_*4);

  dim3 blk(256);
  int g4 = (NB4_ + 255) / 256;          // 512

  hipMemsetAsync(mk, 0, (size_t)N_*8, stream);   // clear 0xAA poison (tag field)
  k_conv_init<<<2048, blk, 0, stream>>>(img, cw, cb, fsum, labels, cnt, psum, mk);
  k_bedge<<<240, blk, 0, stream>>>(fsum, mk);
  k_update<<<g4, blk, 0, stream>>>(mk, 1u, labels, fsum, psum, cnt);

  for (int it = 1; it < 8; ++it) {
    k_simbest<<<g4, blk, 0, stream>>>(labels, fsum, cnt, mk, (unsigned)(it+1));
    k_update<<<g4, blk, 0, stream>>>(mk, (unsigned)(it+1), labels, fsum, psum, cnt);
  }

  float* out = (float*)d_out;
  k_out<<<g4, blk, 0, stream>>>(labels, img, cnt, fsum, psum, lw, lb,
                                out, out + (size_t)N_*C_);
}

// Round 8
// 303.844 us; speedup vs baseline: 1.5537x; 1.5537x over previous
//
#include <hip/hip_runtime.h>

#define B_ 8
#define C_ 3
#define H_ 256
#define W_ 256
#define HID_ 32
#define HW_ (H_*W_)            // 65536
#define N_ (B_*H_*W_)          // 524288
#define K01_ 0xBDCCCCCDu       // fkey(0.1f)
#define TILE_ 16

// XCD-chunked swizzle for 2048-block grids: consecutive hardware dispatch ids
// round-robin across 8 XCDs; this remap gives each XCD one contiguous
// 256-block chunk = one full image -> region atomics stay in one L2.
__device__ __forceinline__ int swz2048(int bid){ return ((bid & 7) << 8) | (bid >> 3); }

__device__ __forceinline__ unsigned fkey(float f){
  unsigned u = __float_as_uint(f);
  return (u & 0x80000000u) ? ~u : (u | 0x80000000u);
}

// mk entry: [63:56]=tag(it+1) | [55:24]=fkey(sim) | [23:0]=neighbor id (N<2^24).
// atomicMax: newer tag always wins; same tag -> (key,id) lexicographic max,
// which is exactly the reference's "max rb among sim==maxsim" tie-break.
__device__ __forceinline__ unsigned long long pack_mk(unsigned tag, unsigned key, int id){
  return ((unsigned long long)tag << 56) | ((unsigned long long)key << 24) | (unsigned)id;
}

__device__ __forceinline__ int parent_dec(unsigned long long m, unsigned tag, int x){
  if ((unsigned)(m >> 56) != tag) return x;
  return ((unsigned)(m >> 24) > K01_) ? (int)(m & 0xFFFFFFu) : x;
}

// 16x16-tile conv + init + it0 in-tile sims (img tile in LDS, sims via wave
// shuffles; lane layout r = wv*4 + (lane>>4), c = lane&15). Cross-tile edges
// handled by k_bedge.
__global__ __launch_bounds__(256) void k_conv_init(const float* __restrict__ img,
    const float* __restrict__ cw, const float* __restrict__ cb,
    float* __restrict__ fsum, int* __restrict__ labels,
    float* __restrict__ cnt, float* __restrict__ psum,
    unsigned long long* __restrict__ mk){
  __shared__ float w_s[HID_*C_*9];
  __shared__ float b_s[HID_];
  __shared__ float img_s[C_][TILE_+2][TILE_+3];   // 3 x 18 x 19
  __shared__ float rowbuf[3*TILE_][33];           // rows 4,8,12 for cross-wave down
  for (int t = threadIdx.x; t < HID_*C_*9; t += blockDim.x) w_s[t] = cw[t];
  if (threadIdx.x < HID_) b_s[threadIdx.x] = cb[threadIdx.x];

  int sb = swz2048(blockIdx.x);
  int b  = sb >> 8;
  int ti = sb & 255;
  int h0 = (ti >> 4) * TILE_;
  int w0 = (ti & 15) * TILE_;

  // stage img tile (18x18x3) with zero padding
  for (int t = threadIdx.x; t < C_*18*18; t += blockDim.x){
    int ci = t / 324; int rm = t - ci*324; int rr = rm / 18; int cc = rm - rr*18;
    int hh = h0 - 1 + rr, ww = w0 - 1 + cc;
    float v = 0.f;
    if (hh >= 0 && hh < H_ && ww >= 0 && ww < W_)
      v = img[(size_t)(b*C_+ci)*HW_ + hh*W_ + ww];
    img_s[ci][rr][cc] = v;
  }
  __syncthreads();

  int lane = threadIdx.x & 63, wv = threadIdx.x >> 6;
  int r = wv*4 + (lane >> 4);
  int c = lane & 15;
  int h = h0 + r, w = w0 + c;
  int i = (b << 16) | (h << 8) | w;

  float patch[C_*9];
  #pragma unroll
  for (int ci=0; ci<C_; ++ci)
    #pragma unroll
    for (int kh=0; kh<3; ++kh)
      #pragma unroll
      for (int kw=0; kw<3; ++kw)
        patch[ci*9+kh*3+kw] = img_s[ci][r+kh][c+kw];

  float acc[HID_];
  #pragma unroll 4
  for (int oc=0; oc<HID_; ++oc){
    float a = b_s[oc];
    const float* ws = w_s + oc*C_*9;
    #pragma unroll
    for (int t=0; t<C_*9; ++t) a += patch[t]*ws[t];
    acc[oc] = a;
  }

  {
    float4* o4 = (float4*)(fsum + (size_t)i*HID_);
    #pragma unroll
    for (int k=0; k<HID_/4; ++k)
      o4[k] = make_float4(acc[4*k], acc[4*k+1], acc[4*k+2], acc[4*k+3]);
  }
  labels[i] = i;
  cnt[i] = 1.0f;
  #pragma unroll
  for (int cc=0; cc<C_; ++cc) psum[(size_t)i*C_+cc] = img_s[cc][r+1][c+1];

  // stage rows 4,8,12 (each wave's lanes 0..15) for cross-wave down edges
  if (wv >= 1 && lane < 16){
    float* dst = rowbuf[(wv-1)*TILE_ + c];
    #pragma unroll
    for (int d=0; d<HID_; ++d) dst[d] = acc[d];
  }

  float d2R = 0.f;
  #pragma unroll
  for (int k=0; k<HID_/4; ++k){
    float t0 = acc[4*k]   - __shfl_down(acc[4*k],  1);
    float t1 = acc[4*k+1] - __shfl_down(acc[4*k+1],1);
    float t2 = acc[4*k+2] - __shfl_down(acc[4*k+2],1);
    float t3 = acc[4*k+3] - __shfl_down(acc[4*k+3],1);
    d2R += t0*t0 + t1*t1 + t2*t2 + t3*t3;
  }
  float d2D = 0.f;
  #pragma unroll
  for (int k=0; k<HID_/4; ++k){
    float t0 = acc[4*k]   - __shfl_down(acc[4*k],  16);
    float t1 = acc[4*k+1] - __shfl_down(acc[4*k+1],16);
    float t2 = acc[4*k+2] - __shfl_down(acc[4*k+2],16);
    float t3 = acc[4*k+3] - __shfl_down(acc[4*k+3],16);
    d2D += t0*t0 + t1*t1 + t2*t2 + t3*t3;
  }
  __syncthreads();
  if (lane >= 48 && wv < 3){          // row 4wv+3: neighbor row held by wave wv+1
    const float* nb = rowbuf[wv*TILE_ + c];
    d2D = 0.f;
    #pragma unroll
    for (int k=0; k<HID_/4; ++k){
      float t0 = acc[4*k]   - nb[4*k];
      float t1 = acc[4*k+1] - nb[4*k+1];
      float t2 = acc[4*k+2] - nb[4*k+2];
      float t3 = acc[4*k+3] - nb[4*k+3];
      d2D += t0*t0 + t1*t1 + t2*t2 + t3*t3;
    }
  }

  if (c < TILE_-1){
    unsigned key = fkey(expf(-d2R));
    atomicMax(mk+i,   pack_mk(1u, key, i+1));
    atomicMax(mk+i+1, pack_mk(1u, key, i));
  }
  if (r < TILE_-1){
    unsigned key = fkey(expf(-d2D));
    atomicMax(mk+i,     pack_mk(1u, key, i+W_));
    atomicMax(mk+i+W_,  pack_mk(1u, key, i));
  }
}

// cross-tile it0 edges: 8 images x {15 boundary cols x 256, 15 boundary rows x 256}
__global__ void k_bedge(const float* __restrict__ fsum,
                        unsigned long long* __restrict__ mk){
  int t = blockIdx.x*blockDim.x + threadIdx.x;
  if (t >= B_*2*15*256) return;
  int y  = t & 255;
  int k  = (t >> 8) % 15;
  int ty = (t >> 8) / 15;
  int b  = ty >> 1, tp = ty & 1;
  int i, j;
  if (tp == 0){ i = (b<<16) | (y<<8) | (16*k+15); j = i+1;  }
  else        { i = (b<<16) | ((16*k+15)<<8) | y; j = i+W_; }
  const float4* fa = (const float4*)(fsum + (size_t)i*HID_);
  const float4* fb = (const float4*)(fsum + (size_t)j*HID_);
  float d2 = 0.f;
  #pragma unroll
  for (int q=0; q<HID_/4; ++q){
    float4 va = fa[q], vb = fb[q];
    float t0 = va.x-vb.x, t1 = va.y-vb.y, t2 = va.z-vb.z, t3 = va.w-vb.w;
    d2 += t0*t0 + t1*t1 + t2*t2 + t3*t3;
  }
  unsigned key = fkey(expf(-d2));
  atomicMax(mk+i, pack_mk(1u, key, j));
  atomicMax(mk+j, pack_mk(1u, key, i));
}

// mid-iteration fused sim+best, 1 px/thread, XCD-swizzled.
__global__ void k_simbest(const int* __restrict__ labels,
                          const float* __restrict__ fsum, const float* __restrict__ cnt,
                          unsigned long long* __restrict__ mk, unsigned tag){
  int i = swz2048(blockIdx.x)*256 + threadIdx.x;
  int rem = i & (HW_-1); int h = rem >> 8; int w = rem & (W_-1);
  int ri = labels[i];
  int rR = (w < W_-1) ? labels[i+1]  : ri;
  int rD = (h < H_-1) ? labels[i+W_] : ri;
  bool eR = (rR != ri), eD = (rD != ri);
  if (!eR && !eD) return;
  float rci = 1.0f / cnt[ri];
  const float4* fi = (const float4*)(fsum + (size_t)ri*HID_);
  float4 mi[HID_/4];
  #pragma unroll
  for (int k=0; k<HID_/4; ++k){
    float4 v = fi[k];
    mi[k] = make_float4(v.x*rci, v.y*rci, v.z*rci, v.w*rci);
  }
  if (eR){
    float rcj = 1.0f / cnt[rR];
    const float4* fj = (const float4*)(fsum + (size_t)rR*HID_);
    float d2 = 0.f;
    #pragma unroll
    for (int k=0; k<HID_/4; ++k){
      float4 v = fj[k];
      float tx = mi[k].x - v.x*rcj; float ty = mi[k].y - v.y*rcj;
      float tz = mi[k].z - v.z*rcj; float tw = mi[k].w - v.w*rcj;
      d2 += tx*tx + ty*ty + tz*tz + tw*tw;
    }
    unsigned key = fkey(expf(-d2));
    atomicMax(mk+ri, pack_mk(tag, key, rR));
    atomicMax(mk+rR, pack_mk(tag, key, ri));
  }
  if (eD){
    float rcj = 1.0f / cnt[rD];
    const float4* fj = (const float4*)(fsum + (size_t)rD*HID_);
    float d2 = 0.f;
    #pragma unroll
    for (int k=0; k<HID_/4; ++k){
      float4 v = fj[k];
      float tx = mi[k].x - v.x*rcj; float ty = mi[k].y - v.y*rcj;
      float tz = mi[k].z - v.z*rcj; float tw = mi[k].w - v.w*rcj;
      d2 += tx*tx + ty*ty + tz*tz + tw*tw;
    }
    unsigned key = fkey(expf(-d2));
    atomicMax(mk+ri, pack_mk(tag, key, rD));
    atomicMax(mk+rD, pack_mk(tag, key, ri));
  }
}

// chase + fold + relabel, 1 px/thread, XCD-swizzled.
__global__ void k_update(const unsigned long long* __restrict__ mk, unsigned tag,
                         int* __restrict__ labels,
                         float* __restrict__ fsum, float* __restrict__ psum,
                         float* __restrict__ cnt){
  int i = swz2048(blockIdx.x)*256 + threadIdx.x;
  int l = labels[i];
  int x = l;
  for (int it = 0; it < (1<<20); ++it){
    int p = parent_dec(mk[x], tag, x);
    if (p == x) break;
    int pp = parent_dec(mk[p], tag, p);
    if (pp == x && x < p) break;     // broken 2-cycle: x is the root
    x = p;
  }
  if (l == i && x != i){             // dying root: fold into surviving root
    atomicAdd(cnt+x, cnt[i]);
    const float* s = fsum + (size_t)i*HID_;
    float* ds = fsum + (size_t)x*HID_;
    #pragma unroll
    for (int d=0; d<HID_; ++d) atomicAdd(ds+d, s[d]);
    const float* ps = psum + (size_t)i*C_;
    float* dp = psum + (size_t)x*C_;
    #pragma unroll
    for (int cc=0; cc<C_; ++cc) atomicAdd(dp+cc, ps[cc]);
  }
  labels[i] = x;
}

// finalize: region feature recomputed at root (roots L2-hot within the XCD's
// image slab), mean injection, labels as float.
__global__ __launch_bounds__(256) void k_out(const int* __restrict__ labels,
      const float* __restrict__ img, const float* __restrict__ cnt,
      const float* __restrict__ fsum, const float* __restrict__ psum,
      const float* __restrict__ lw, const float* __restrict__ lb,
      float* __restrict__ out, float* __restrict__ outlab){
  __shared__ float lw_s[C_*HID_];
  __shared__ float lb_s[C_];
  for (int t = threadIdx.x; t < C_*HID_; t += blockDim.x) lw_s[t] = lw[t];
  if (threadIdx.x < C_) lb_s[threadIdx.x] = lb[threadIdx.x];
  __syncthreads();
  int i = swz2048(blockIdx.x)*256 + threadIdx.x;
  int l = labels[i];
  float rc = 1.0f / cnt[l];
  const float* s = fsum + (size_t)l*HID_;
  float rf[C_];
  #pragma unroll
  for (int cc=0; cc<C_; ++cc){
    float a = 0.f;
    const float* wv = lw_s + cc*HID_;
    #pragma unroll
    for (int d=0; d<HID_; ++d) a += (s[d]*rc)*wv[d];
    rf[cc] = (a + lb_s[cc]) - psum[(size_t)l*C_+cc]*rc;
  }
  int b = i >> 16; int rem = i & (HW_-1);
  const float* ip = img + (size_t)b*C_*HW_ + rem;
  #pragma unroll
  for (int cc=0; cc<C_; ++cc)
    out[(size_t)i*C_+cc] = ip[(size_t)cc*HW_] + rf[cc];
  outlab[i] = (float)l;
}

extern "C" void kernel_launch(void* const* d_in, const int* in_sizes, int n_in,
                              void* d_out, int out_size, void* d_ws, size_t ws_size,
                              hipStream_t stream) {
  const float* img = (const float*)d_in[0];
  const float* cw  = (const float*)d_in[1];
  const float* cb  = (const float*)d_in[2];
  const float* lw  = (const float*)d_in[3];
  const float* lb  = (const float*)d_in[4];

  char* ws = (char*)d_ws;
  size_t off = 0;
  auto alloc = [&](size_t bytes) -> void* {
    void* p = ws + off; off += (bytes + 255) & ~(size_t)255; return p;
  };
  float*              fsum   = (float*)              alloc((size_t)N_*HID_*4);
  float*              psum   = (float*)              alloc((size_t)N_*C_*4);
  float*              cnt    = (float*)              alloc((size_t)N_*4);
  unsigned long long* mk     = (unsigned long long*) alloc((size_t)N_*8);
  int*                labels = (int*)                alloc((size_t)N_*4);

  dim3 blk(256);
  const int gN = 2048;

  hipMemsetAsync(mk, 0, (size_t)N_*8, stream);   // clear 0xAA poison (tag field)
  k_conv_init<<<gN, blk, 0, stream>>>(img, cw, cb, fsum, labels, cnt, psum, mk);
  k_bedge<<<240, blk, 0, stream>>>(fsum, mk);
  k_update<<<gN, blk, 0, stream>>>(mk, 1u, labels, fsum, psum, cnt);

  for (int it = 1; it < 8; ++it) {
    k_simbest<<<gN, blk, 0, stream>>>(labels, fsum, cnt, mk, (unsigned)(it+1));
    k_update<<<gN, blk, 0, stream>>>(mk, (unsigned)(it+1), labels, fsum, psum, cnt);
  }

  float* out = (float*)d_out;
  k_out<<<gN, blk, 0, stream>>>(labels, img, cnt, fsum, psum, lw, lb,
                                out, out + (size_t)N_*C_);
}